// Round 13
// baseline (305.972 us; speedup 1.0000x reference)
//
#include <hip/hip_runtime.h>
#include <hip/hip_bf16.h>
#include <stdint.h>

// Problem: B=1, S=4096, HIDDEN=2048, HEADS=16, HEAD_DIM=128, causal MHA.
// All inputs fp32; output fp32. Compute in bf16 MFMA with fp32 accum.
//
// Workspace layout (bytes), total ~112 MB:
//   xb    [4096][2048] bf16 @ 0         (16 MB)
//   WTall [4][2048][2048] bf16 @ 16 MB  (32 MB: WqT,WkT,WvT,WoT transposed [out][in])
//   Qb    [4096][2048] bf16 @ 48 MB
//   Kb    [4096][2048] bf16 @ 64 MB
//   VTb   [2048][4096] bf16 @ 80 MB     (V transposed per-head: row h*128+d, col s)
//   Ctx   [4096][2048] bf16 @ 96 MB

#define SQ 4096
#define HID 2048
#define NH 16
#define HD 128

typedef __attribute__((ext_vector_type(8))) short bf16x8;
typedef __attribute__((ext_vector_type(4))) float f32x4;
typedef __attribute__((ext_vector_type(4))) unsigned short us4;

__device__ inline unsigned short f2bf(float f) {
    unsigned int u = __builtin_bit_cast(unsigned int, f);
    u = (u + 0x7FFFu + ((u >> 16) & 1u)) >> 16;
    return (unsigned short)u;
}

__device__ inline void gl2lds16(const void* g, void* l) {
    __builtin_amdgcn_global_load_lds(
        (const __attribute__((address_space(1))) unsigned int*)g,
        (__attribute__((address_space(3))) unsigned int*)l, 16, 0, 0);
}

// ---- merged preprocessing: z<4 -> transpose+convert W_z; z=4 -> cvt x ------
__global__ void prep(const float* __restrict__ x, const float* __restrict__ W0,
                     const float* __restrict__ W1, const float* __restrict__ W2,
                     const float* __restrict__ W3, unsigned short* __restrict__ xb,
                     unsigned short* __restrict__ WTall) {
    __shared__ float tile[64][65];
    int t = threadIdx.x;
    if (blockIdx.z == 4) {
        int bid = blockIdx.y * 32 + blockIdx.x;
        for (int it = 0; it < 8; it++) {
            int i = (bid * 256 + t + it * 262144) * 4;
            float4 v = *(const float4*)(x + i);
            us4 o;
            o.x = f2bf(v.x); o.y = f2bf(v.y); o.z = f2bf(v.z); o.w = f2bf(v.w);
            *(us4*)(xb + i) = o;
        }
        return;
    }
    const float* W = (blockIdx.z == 0) ? W0 : (blockIdx.z == 1) ? W1
                   : (blockIdx.z == 2) ? W2 : W3;
    unsigned short* WT = WTall + (size_t)blockIdx.z * HID * HID;
    int n0 = blockIdx.x * 64, k0 = blockIdx.y * 64;
    for (int i = 0; i < 4; i++) {
        int idx = i * 256 + t;
        int k = idx >> 4;
        int n4 = (idx & 15) << 2;
        float4 v = *(const float4*)(W + (size_t)(k0 + k) * HID + n0 + n4);
        tile[k][n4 + 0] = v.x; tile[k][n4 + 1] = v.y;
        tile[k][n4 + 2] = v.z; tile[k][n4 + 3] = v.w;
    }
    __syncthreads();
    for (int i = 0; i < 4; i++) {
        int idx = i * 256 + t;
        int n = idx >> 4;
        int k4 = (idx & 15) << 2;
        us4 o;
        o.x = f2bf(tile[k4 + 0][n]); o.y = f2bf(tile[k4 + 1][n]);
        o.z = f2bf(tile[k4 + 2][n]); o.w = f2bf(tile[k4 + 3][n]);
        *(us4*)(WT + (size_t)(n0 + n) * HID + k0 + k4) = o;
    }
}

// ---------------- phase-structured bf16 GEMM (T2+T3+T4+T5) ------------------
// BM=256, BN=128, BK=64, 512 thr = 8 waves (4m x 2n), wave tile 64x64.
// 3 LDS buffers (144 KB), depth-2 prefetch: during tile t we stage tile t+2
// into buf (t+2)%3 (last read at tile t-1; reads done before t's barrier).
// ONE counted vmcnt per K-tile: vmcnt(6) leaves tile-(t+1)'s 6 loads in
// flight (T4 - never drain to 0 until last tile). Every wave counts down
// before the shared barrier => all waves' tile-t loads landed => buffer valid.
// 2 phases per K-tile, each {ds_read burst || stage -> lgkmcnt(0) +
// sched_barrier -> setprio(1), 16 MFMA, setprio(0) -> barrier} (T3/T5; the
// per-phase interleave is the m196 lever missing from round-6's attempt).
// Zero-conflict slot^(row&7) LDS swizzle, both sides (T2, verified round 8).
// OUTKIND 0: fused QKV (proj = by>>4; Q/K bf16 [M][N]+bias, V bf16 [N][M]+bias)
// OUTKIND 1: f32 out [M][N], no bias (proj=3 -> Wo).
template <int OUTKIND>
__global__ __launch_bounds__(512) void gemm8(
    const unsigned short* __restrict__ A, const unsigned short* __restrict__ WTall,
    const float* __restrict__ bq, const float* __restrict__ bk,
    const float* __restrict__ bv, unsigned short* __restrict__ Qb,
    unsigned short* __restrict__ Kb, unsigned short* __restrict__ VTb,
    float* __restrict__ Cf) {
    const int K = 2048, NT = 32, M = 4096, N = 2048;
    __shared__ __align__(16) unsigned short AL[3][256 * 64];   // 96 KB
    __shared__ __align__(16) unsigned short BL[3][128 * 64];   // 48 KB
    int m0 = blockIdx.x * 256;
    int proj = (OUTKIND == 0) ? ((int)blockIdx.y >> 4) : 3;
    int n0 = ((int)blockIdx.y & 15) * 128;
    const unsigned short* BT = WTall + (size_t)proj * HID * HID;
    int t = threadIdx.x, lane = t & 63, w = t >> 6;
    int lr = lane & 15, hi = lane >> 4;
    int wm = w >> 1, wn = w & 1;

    // stage: linear LDS dest (gl2lds rule), inverse-swizzled global source.
    auto stageA = [&](int buf, int k0) {
#pragma unroll
        for (int i = 0; i < 4; i++) {
            int idx = i * 512 + t, r = idx >> 3, s = idx & 7;   // 256 rows x 8 slots
            gl2lds16(A + (size_t)(m0 + r) * K + k0 + ((s ^ (r & 7)) << 3),
                     (void*)(&AL[buf][(i * 512 + w * 64) << 3]));
        }
    };
    auto stageB = [&](int buf, int k0) {
#pragma unroll
        for (int i = 0; i < 2; i++) {
            int idx = i * 512 + t, r = idx >> 3, s = idx & 7;   // 128 rows x 8 slots
            gl2lds16(BT + (size_t)(n0 + r) * K + k0 + ((s ^ (r & 7)) << 3),
                     (void*)(&BL[buf][(i * 512 + w * 64) << 3]));
        }
    };

    f32x4 acc[4][4] = {};
    stageA(0, 0); stageB(0, 0);        // tile 0: 6 loads
    stageA(1, 64); stageB(1, 64);      // tile 1: 6 loads

    for (int tt = 0; tt < NT; ++tt) {
        int c = tt % 3;
        if (tt < NT - 1) asm volatile("s_waitcnt vmcnt(6)" ::: "memory");
        else             asm volatile("s_waitcnt vmcnt(0)" ::: "memory");
        __builtin_amdgcn_s_barrier();
        __builtin_amdgcn_sched_barrier(0);
        const unsigned short* Al = &AL[c][0];
        const unsigned short* Bl = &BL[c][0];

        // ---- phase 0: read A-frags + B-frags(nf0,1); stage A(t+2); MFMA ----
        bf16x8 af[2][4], bf0[2][2];
#pragma unroll
        for (int kk = 0; kk < 2; ++kk) {
            int sl = ((kk * 4 + hi) ^ (lr & 7)) << 3;
#pragma unroll
            for (int mf = 0; mf < 4; ++mf)
                af[kk][mf] = *(const bf16x8*)(Al + (wm * 64 + mf * 16 + lr) * 64 + sl);
#pragma unroll
            for (int nf = 0; nf < 2; ++nf)
                bf0[kk][nf] = *(const bf16x8*)(Bl + (wn * 64 + nf * 16 + lr) * 64 + sl);
        }
        if (tt + 2 < NT) stageA((tt + 2) % 3, (tt + 2) * 64);
        asm volatile("s_waitcnt lgkmcnt(0)" ::: "memory");
        __builtin_amdgcn_sched_barrier(0);
        __builtin_amdgcn_s_setprio(1);
#pragma unroll
        for (int kk = 0; kk < 2; ++kk)
#pragma unroll
            for (int mf = 0; mf < 4; ++mf)
#pragma unroll
                for (int nf = 0; nf < 2; ++nf)
                    acc[mf][nf] = __builtin_amdgcn_mfma_f32_16x16x32_bf16(
                        af[kk][mf], bf0[kk][nf], acc[mf][nf], 0, 0, 0);
        __builtin_amdgcn_s_setprio(0);
        __builtin_amdgcn_s_barrier();

        // ---- phase 1: read B-frags(nf2,3); stage B(t+2); MFMA --------------
        bf16x8 bf1[2][2];
#pragma unroll
        for (int kk = 0; kk < 2; ++kk) {
            int sl = ((kk * 4 + hi) ^ (lr & 7)) << 3;
#pragma unroll
            for (int nf = 0; nf < 2; ++nf)
                bf1[kk][nf] = *(const bf16x8*)(Bl + (wn * 64 + (nf + 2) * 16 + lr) * 64 + sl);
        }
        if (tt + 2 < NT) stageB((tt + 2) % 3, (tt + 2) * 64);
        asm volatile("s_waitcnt lgkmcnt(0)" ::: "memory");
        __builtin_amdgcn_sched_barrier(0);
        __builtin_amdgcn_s_setprio(1);
#pragma unroll
        for (int kk = 0; kk < 2; ++kk)
#pragma unroll
            for (int mf = 0; mf < 4; ++mf)
#pragma unroll
                for (int nf = 0; nf < 2; ++nf)
                    acc[mf][nf + 2] = __builtin_amdgcn_mfma_f32_16x16x32_bf16(
                        af[kk][mf], bf1[kk][nf], acc[mf][nf + 2], 0, 0, 0);
        __builtin_amdgcn_s_setprio(0);
        // no trailing barrier: next tile opens with vmcnt+barrier; the buffer
        // staged next (t+3 -> buf t%3) is only read again at tile t+3.
    }

    int rbase = hi << 2;
    if (OUTKIND == 0) {
        const float* bias = (proj == 0) ? bq : (proj == 1) ? bk : bv;
        for (int mf = 0; mf < 4; mf++) {
            for (int nf = 0; nf < 4; nf++) {
                int n_g = n0 + wn * 64 + nf * 16 + lr;
                int m_base = m0 + wm * 64 + mf * 16 + rbase;
                float b = bias[n_g];
                if (proj < 2) {
                    unsigned short* Cb = proj ? Kb : Qb;
                    for (int r = 0; r < 4; r++)
                        Cb[(size_t)(m_base + r) * N + n_g] = f2bf(acc[mf][nf][r] + b);
                } else {
                    us4 o;
                    o.x = f2bf(acc[mf][nf][0] + b); o.y = f2bf(acc[mf][nf][1] + b);
                    o.z = f2bf(acc[mf][nf][2] + b); o.w = f2bf(acc[mf][nf][3] + b);
                    *(us4*)(VTb + (size_t)n_g * M + m_base) = o;
                }
            }
        }
    } else {
        for (int mf = 0; mf < 4; mf++)
            for (int nf = 0; nf < 4; nf++) {
                int n_g = n0 + wn * 64 + nf * 16 + lr;
                int m_base = m0 + wm * 64 + mf * 16 + rbase;
                for (int r = 0; r < 4; r++)
                    Cf[(size_t)(m_base + r) * N + n_g] = acc[mf][nf][r];
            }
    }
}

// ---------------- causal flash attention (v7 + setprio, verified 146us) ------
// grid (NH, 16); 512 thr = 8 waves; QBLK=128; block (h, by) processes strips
// {31-by, by} sequentially -> exactly 33 identical KV-tile iterations per
// block, 256 blocks, 1/CU. 128 KB LDS (dbuf K[128x128] + VT[128x128]).
// Swapped math (S^T = mfma(K,Q)), in-lane softmax, in-register P (cvt_pk +
// shfl), T13 defer-max, LDS-scratch epilogue.
__global__ __launch_bounds__(512) void attn(
    const unsigned short* __restrict__ Q, const unsigned short* __restrict__ Kc,
    const unsigned short* __restrict__ VT, unsigned short* __restrict__ O) {
    __shared__ __align__(16) unsigned short SMEM[65536];   // 128 KB
    unsigned short* KB = SMEM;              // [2][128*128]
    unsigned short* VB = SMEM + 32768;      // [2][128*128]
    int h = blockIdx.x;
    int by = blockIdx.y;
    int t = threadIdx.x, lane = t & 63, w = t >> 6;
    int lr = lane & 15, hi = lane >> 4;
    const float scale = 0.08838834764831845f;  // 1/sqrt(128)

    auto stage = [&](int buf, int kv0) {
#pragma unroll
        for (int i = 0; i < 4; i++) {
            int idx = i * 512 + t;            // 0..2047
            int r = idx >> 4, s = idx & 15;   // K: 128 rows x 16 slots
            gl2lds16(Kc + (size_t)(kv0 + r) * HID + h * HD + ((s ^ (r & 7)) << 3),
                     (void*)(KB + buf * 16384 + ((i * 512 + w * 64) << 3)));
        }
#pragma unroll
        for (int i = 0; i < 4; i++) {
            int idx = i * 512 + t;
            int r = idx >> 4, s = idx & 15;   // VT: 128 rows x 16 slots
            gl2lds16(VT + (size_t)(h * HD + r) * SQ + kv0 + ((s ^ (r & 7)) << 3),
                     (void*)(VB + buf * 16384 + ((i * 512 + w * 64) << 3)));
        }
    };

    int strips[2] = {31 - by, by};
    for (int sp = 0; sp < 2; sp++) {
        int strip = strips[sp];
        int qbase = strip * 128;
        int wq0 = qbase + w * 16;
        int qg = wq0 + lr;                 // this lane's q row

        stage(0, 0);
        bf16x8 qf[4];
        for (int ks = 0; ks < 4; ks++)
            qf[ks] = *(const bf16x8*)(Q + (size_t)qg * HID + h * HD + ks * 32 + (hi << 3));
        f32x4 o_acc[8] = {};               // O^T frags: d=16c2+4hi+reg, q=lane&15
        float m_r = -1e30f, l_r = 0.f;
        __syncthreads();

        int nt = strip + 1;                // 128-wide KV tiles for this strip
        int cur = 0;
        for (int tile = 0; tile < nt; tile++) {
            int kv0 = tile * 128;
            if (tile + 1 < nt) stage(cur ^ 1, kv0 + 128);   // async prefetch
            const unsigned short* Kl = KB + cur * 16384;
            const unsigned short* Vl = VB + cur * 16384;

            if (kv0 <= wq0 + 15) {   // not fully above this wave's diagonal
                // S^T = mfma(K, Q): sfr[c][r] = S^T[k=16c+4hi+r][q=lane&15]
                f32x4 sfr[8];
#pragma unroll
                for (int c = 0; c < 8; c++) {
                    f32x4 s = {0.f, 0.f, 0.f, 0.f};
                    __builtin_amdgcn_s_setprio(1);
#pragma unroll
                    for (int ks = 0; ks < 4; ks++) {
                        bf16x8 kf = *(const bf16x8*)(Kl + (c * 16 + lr) * 128 +
                                                     (((ks * 4 + hi) ^ (lr & 7)) << 3));
                        s = __builtin_amdgcn_mfma_f32_16x16x32_bf16(kf, qf[ks], s, 0, 0, 0);
                    }
                    __builtin_amdgcn_s_setprio(0);
                    sfr[c] = s;
                }
                // scale + causal mask (k_g <= q_g)
                if (kv0 + 127 > wq0) {
#pragma unroll
                    for (int c = 0; c < 8; c++) {
                        int kgb = kv0 + c * 16 + 4 * hi;
                        for (int r = 0; r < 4; r++) {
                            float v = sfr[c][r] * scale;
                            sfr[c][r] = (kgb + r <= qg) ? v : -1e30f;
                        }
                    }
                } else {
#pragma unroll
                    for (int c = 0; c < 8; c++)
                        for (int r = 0; r < 4; r++) sfr[c][r] *= scale;
                }
                // in-lane row max (32 values) + cross-hi (2 shfl_xor)
                float mx = -1e30f;
#pragma unroll
                for (int c = 0; c < 8; c++)
                    mx = fmaxf(mx, fmaxf(fmaxf(sfr[c][0], sfr[c][1]),
                                         fmaxf(sfr[c][2], sfr[c][3])));
                mx = fmaxf(mx, __shfl_xor(mx, 16));
                mx = fmaxf(mx, __shfl_xor(mx, 32));
                // T13 defer-max
                if (__all((mx - m_r) <= 8.0f)) {
                    float rs = 0.f;
#pragma unroll
                    for (int c = 0; c < 8; c++)
                        for (int r = 0; r < 4; r++) {
                            float p = __expf(sfr[c][r] - m_r);
                            sfr[c][r] = p;
                            rs += p;
                        }
                    rs += __shfl_xor(rs, 16);
                    rs += __shfl_xor(rs, 32);
                    l_r += rs;
                } else {
                    float mn = fmaxf(m_r, mx);
                    float alpha = __expf(m_r - mn);
                    m_r = mn;
                    float rs = 0.f;
#pragma unroll
                    for (int c = 0; c < 8; c++)
                        for (int r = 0; r < 4; r++) {
                            float p = __expf(sfr[c][r] - mn);
                            sfr[c][r] = p;
                            rs += p;
                        }
                    rs += __shfl_xor(rs, 16);
                    rs += __shfl_xor(rs, 32);
                    l_r = l_r * alpha + rs;
                    for (int c2 = 0; c2 < 8; c2++)
                        for (int r = 0; r < 4; r++) o_acc[c2][r] *= alpha;
                }

                // P^T -> PV B-operand fragments, fully in-register.
                unsigned int wpk[8][2];
#pragma unroll
                for (int c = 0; c < 8; c++)
#pragma unroll
                    for (int i = 0; i < 2; i++) {
                        unsigned int d;
                        asm("v_cvt_pk_bf16_f32 %0, %1, %2"
                            : "=v"(d) : "v"(sfr[c][2 * i]), "v"(sfr[c][2 * i + 1]));
                        wpk[c][i] = d;
                    }
                int srcA = lr + ((hi & 1) << 5);
                int srcB = srcA + 16;
                bool sel = (hi & 2);
#pragma unroll
                for (int kk = 0; kk < 4; kk++) {
                    unsigned int a0 = __shfl(wpk[2 * kk][0], srcA);
                    unsigned int a1 = __shfl(wpk[2 * kk][1], srcA);
                    unsigned int a2 = __shfl(wpk[2 * kk][0], srcB);
                    unsigned int a3 = __shfl(wpk[2 * kk][1], srcB);
                    unsigned int b0 = __shfl(wpk[2 * kk + 1][0], srcA);
                    unsigned int b1 = __shfl(wpk[2 * kk + 1][1], srcA);
                    unsigned int b2 = __shfl(wpk[2 * kk + 1][0], srcB);
                    unsigned int b3 = __shfl(wpk[2 * kk + 1][1], srcB);
                    union { unsigned int u[4]; bf16x8 v; } pf;
                    pf.u[0] = sel ? b0 : a0;
                    pf.u[1] = sel ? b1 : a1;
                    pf.u[2] = sel ? b2 : a2;
                    pf.u[3] = sel ? b3 : a3;
                    // O^T += V^T @ P^T : A = V^T (rows d), B = P^T frag
                    __builtin_amdgcn_s_setprio(1);
#pragma unroll
                    for (int c2 = 0; c2 < 8; c2++) {
                        bf16x8 vv = *(const bf16x8*)(Vl + (c2 * 16 + lr) * 128 +
                                                     (((kk * 4 + hi) ^ (lr & 7)) << 3));
                        o_acc[c2] = __builtin_amdgcn_mfma_f32_16x16x32_bf16(
                            vv, pf.v, o_acc[c2], 0, 0, 0);
                    }
                    __builtin_amdgcn_s_setprio(0);
                }
            }
            __syncthreads();   // drains prefetch vmcnt + syncs buffer flip
            cur ^= 1;
        }

        // epilogue: O^T -> O via per-wave bf16 LDS scratch (within-wave only).
        unsigned short* scr = SMEM + w * 2176;   // 16 rows x 136 bf16
        float invl = 1.0f / l_r;
        for (int c2 = 0; c2 < 8; c2++) {
            us4 o;
            o.x = f2bf(o_acc[c2][0] * invl); o.y = f2bf(o_acc[c2][1] * invl);
            o.z = f2bf(o_acc[c2][2] * invl); o.w = f2bf(o_acc[c2][3] * invl);
            *(us4*)(scr + lr * 136 + c2 * 16 + hi * 4) = o;
        }
        for (int j = 0; j < 4; j++) {
            bf16x8 v = *(const bf16x8*)(scr + lr * 136 + hi * 32 + j * 8);
            *(bf16x8*)(O + (size_t)qg * HID + h * HD + hi * 32 + j * 8) = v;
        }
        __syncthreads();   // scratch reads done before next strip re-stages
    }
}

// ---------------------------------------------------------------------------
extern "C" void kernel_launch(void* const* d_in, const int* in_sizes, int n_in,
                              void* d_out, int out_size, void* d_ws, size_t ws_size,
                              hipStream_t stream) {
    const float* x  = (const float*)d_in[0];
    const float* Wq = (const float*)d_in[1];
    const float* bq = (const float*)d_in[2];
    const float* Wk = (const float*)d_in[3];
    const float* bk = (const float*)d_in[4];
    const float* Wv = (const float*)d_in[5];
    const float* bv = (const float*)d_in[6];
    const float* Wo = (const float*)d_in[7];

    char* ws = (char*)d_ws;
    const size_t MB = 1024 * 1024;
    unsigned short* xb    = (unsigned short*)(ws + 0 * MB);
    unsigned short* WTall = (unsigned short*)(ws + 16 * MB);   // 4 x 8 MB
    unsigned short* Qb    = (unsigned short*)(ws + 48 * MB);
    unsigned short* Kbuf  = (unsigned short*)(ws + 64 * MB);
    unsigned short* VTb   = (unsigned short*)(ws + 80 * MB);
    unsigned short* Ctx   = (unsigned short*)(ws + 96 * MB);

    // 1. merged preprocessing: x -> bf16 (z=4) + 4 weights -> WT bf16 (z<4)
    prep<<<dim3(32, 32, 5), 256, 0, stream>>>(x, Wq, Wk, Wv, Wo, xb, WTall);
    // 2. fused QKV projections (768 blocks = 3 exact rounds, 1 block/CU)
    gemm8<0><<<dim3(16, 48), 512, 0, stream>>>(xb, WTall, bq, bk, bv,
                                               Qb, Kbuf, VTb, nullptr);
    // 3. causal attention (256 identical blocks, 1/CU, v7 + setprio)
    attn<<<dim3(NH, 16), 512, 0, stream>>>(Qb, Kbuf, VTb, Ctx);
    // 4. output projection (256 blocks = 1 exact round)
    gemm8<1><<<dim3(16, 16), 512, 0, stream>>>(Ctx, WTall, nullptr, nullptr,
                                               nullptr, nullptr, nullptr,
                                               nullptr, (float*)d_out);
}

// Round 14
// 295.987 us; speedup vs baseline: 1.0337x; 1.0337x over previous
//
#include <hip/hip_runtime.h>
#include <hip/hip_bf16.h>
#include <stdint.h>

// Problem: B=1, S=4096, HIDDEN=2048, HEADS=16, HEAD_DIM=128, causal MHA.
// All inputs fp32; output fp32. Compute in bf16 MFMA with fp32 accum.
//
// Workspace layout (bytes), total ~112 MB:
//   xb    [4096][2048] bf16 @ 0         (16 MB)
//   WTall [4][2048][2048] bf16 @ 16 MB  (32 MB: WqT,WkT,WvT,WoT transposed [out][in])
//   Qb    [4096][2048] bf16 @ 48 MB    (PRE-SCALED by 1/sqrt(128)*log2(e))
//   Kb    [4096][2048] bf16 @ 64 MB
//   VTb   [2048][4096] bf16 @ 80 MB     (V transposed per-head: row h*128+d, col s)
//   Ctx   [4096][2048] bf16 @ 96 MB

#define SQ 4096
#define HID 2048
#define NH 16
#define HD 128

typedef __attribute__((ext_vector_type(8))) short bf16x8;
typedef __attribute__((ext_vector_type(4))) float f32x4;
typedef __attribute__((ext_vector_type(4))) unsigned short us4;

__device__ inline unsigned short f2bf(float f) {
    unsigned int u = __builtin_bit_cast(unsigned int, f);
    u = (u + 0x7FFFu + ((u >> 16) & 1u)) >> 16;
    return (unsigned short)u;
}

__device__ inline void gl2lds16(const void* g, void* l) {
    __builtin_amdgcn_global_load_lds(
        (const __attribute__((address_space(1))) unsigned int*)g,
        (__attribute__((address_space(3))) unsigned int*)l, 16, 0, 0);
}

// ---- merged preprocessing: z<4 -> transpose+convert W_z; z=4 -> cvt x ------
__global__ void prep(const float* __restrict__ x, const float* __restrict__ W0,
                     const float* __restrict__ W1, const float* __restrict__ W2,
                     const float* __restrict__ W3, unsigned short* __restrict__ xb,
                     unsigned short* __restrict__ WTall) {
    __shared__ float tile[64][65];
    int t = threadIdx.x;
    if (blockIdx.z == 4) {
        int bid = blockIdx.y * 32 + blockIdx.x;
        for (int it = 0; it < 8; it++) {
            int i = (bid * 256 + t + it * 262144) * 4;
            float4 v = *(const float4*)(x + i);
            us4 o;
            o.x = f2bf(v.x); o.y = f2bf(v.y); o.z = f2bf(v.z); o.w = f2bf(v.w);
            *(us4*)(xb + i) = o;
        }
        return;
    }
    const float* W = (blockIdx.z == 0) ? W0 : (blockIdx.z == 1) ? W1
                   : (blockIdx.z == 2) ? W2 : W3;
    unsigned short* WT = WTall + (size_t)blockIdx.z * HID * HID;
    int n0 = blockIdx.x * 64, k0 = blockIdx.y * 64;
    for (int i = 0; i < 4; i++) {
        int idx = i * 256 + t;
        int k = idx >> 4;
        int n4 = (idx & 15) << 2;
        float4 v = *(const float4*)(W + (size_t)(k0 + k) * HID + n0 + n4);
        tile[k][n4 + 0] = v.x; tile[k][n4 + 1] = v.y;
        tile[k][n4 + 2] = v.z; tile[k][n4 + 3] = v.w;
    }
    __syncthreads();
    for (int i = 0; i < 4; i++) {
        int idx = i * 256 + t;
        int n = idx >> 4;
        int k4 = (idx & 15) << 2;
        us4 o;
        o.x = f2bf(tile[k4 + 0][n]); o.y = f2bf(tile[k4 + 1][n]);
        o.z = f2bf(tile[k4 + 2][n]); o.w = f2bf(tile[k4 + 3][n]);
        *(us4*)(WT + (size_t)(n0 + n) * HID + k0 + k4) = o;
    }
}

// ---------------- pipelined bf16 GEMM (2 blocks/CU for TLP overlap) ---------
// BM=BN=128, BK=64, 256 thr = 4 waves (2m x 2n), wave tile 64x64.
// 2 LDS buffers (64 KB) -> 2 blocks/CU. Issue-early/wait-late staging.
// Zero-conflict LDS slot^(row&7) swizzle (both sides). setprio on MFMA.
// OUTKIND 0: fused QKV (proj = by>>4; Q/K bf16 [M][N]+bias, V bf16 [N][M]+bias;
//            Q is PRE-SCALED by 1/sqrt(HD)*log2(e) for base-2 softmax in attn)
// OUTKIND 1: f32 out [M][N], no bias (proj=3 -> Wo).
template <int OUTKIND>
__global__ __launch_bounds__(256) void gemm_pipe(
    const unsigned short* __restrict__ A, const unsigned short* __restrict__ WTall,
    const float* __restrict__ bq, const float* __restrict__ bk,
    const float* __restrict__ bv, unsigned short* __restrict__ Qb,
    unsigned short* __restrict__ Kb, unsigned short* __restrict__ VTb,
    float* __restrict__ Cf) {
    const int K = 2048, NT = 32, M = 4096, N = 2048;
    __shared__ __align__(16) unsigned short AL[2][128 * 64];
    __shared__ __align__(16) unsigned short BL[2][128 * 64];
    int m0 = blockIdx.x * 128;
    int proj = (OUTKIND == 0) ? ((int)blockIdx.y >> 4) : 3;
    int n0 = (OUTKIND == 0) ? ((int)blockIdx.y & 15) * 128 : (int)blockIdx.y * 128;
    const unsigned short* BT = WTall + (size_t)proj * HID * HID;
    int t = threadIdx.x, lane = t & 63, w = t >> 6;
    int lr = lane & 15, hi = lane >> 4;
    int wm = w >> 1, wn = w & 1;

    auto stage = [&](int buf, int k0) {
#pragma unroll
        for (int i = 0; i < 4; i++) {
            int idx = i * 256 + t, r = idx >> 3, s = idx & 7;
            gl2lds16(A + (size_t)(m0 + r) * K + k0 + ((s ^ (r & 7)) << 3),
                     (void*)(&AL[buf][(i * 256 + w * 64) << 3]));
        }
#pragma unroll
        for (int i = 0; i < 4; i++) {
            int idx = i * 256 + t, r = idx >> 3, s = idx & 7;
            gl2lds16(BT + (size_t)(n0 + r) * K + k0 + ((s ^ (r & 7)) << 3),
                     (void*)(&BL[buf][(i * 256 + w * 64) << 3]));
        }
    };

    f32x4 acc[4][4] = {};
    stage(0, 0);

    for (int tt = 0; tt < NT; ++tt) {
        int c = tt & 1;
        asm volatile("s_waitcnt vmcnt(0)" ::: "memory");  // tile tt landed
        __builtin_amdgcn_s_barrier();
        __builtin_amdgcn_sched_barrier(0);
        if (tt + 1 < NT) stage(c ^ 1, (tt + 1) * 64);     // issue early
        const unsigned short* Al = &AL[c][0];
        const unsigned short* Bl = &BL[c][0];
#pragma unroll
        for (int kk = 0; kk < 2; ++kk) {
            int sl = ((kk * 4 + hi) ^ (lr & 7)) << 3;
            bf16x8 af[4], bfg[4];
#pragma unroll
            for (int mf = 0; mf < 4; ++mf)
                af[mf] = *(const bf16x8*)(Al + (wm * 64 + mf * 16 + lr) * 64 + sl);
#pragma unroll
            for (int nf = 0; nf < 4; ++nf)
                bfg[nf] = *(const bf16x8*)(Bl + (wn * 64 + nf * 16 + lr) * 64 + sl);
            __builtin_amdgcn_s_setprio(1);
#pragma unroll
            for (int mf = 0; mf < 4; ++mf)
#pragma unroll
                for (int nf = 0; nf < 4; ++nf)
                    acc[mf][nf] = __builtin_amdgcn_mfma_f32_16x16x32_bf16(
                        af[mf], bfg[nf], acc[mf][nf], 0, 0, 0);
            __builtin_amdgcn_s_setprio(0);
        }
    }

    int rbase = hi << 2;
    if (OUTKIND == 0) {
        const float* bias = (proj == 0) ? bq : (proj == 1) ? bk : bv;
        // Q pre-scale: S*log2e folded in so attn softmax runs native exp2.
        const float qs = (proj == 0) ? (0.08838834764831845f * 1.4426950408889634f)
                                     : 1.0f;
        for (int mf = 0; mf < 4; mf++) {
            for (int nf = 0; nf < 4; nf++) {
                int n_g = n0 + wn * 64 + nf * 16 + lr;
                int m_base = m0 + wm * 64 + mf * 16 + rbase;
                float b = bias[n_g];
                if (proj < 2) {
                    unsigned short* Cb = proj ? Kb : Qb;
                    for (int r = 0; r < 4; r++)
                        Cb[(size_t)(m_base + r) * N + n_g] = f2bf((acc[mf][nf][r] + b) * qs);
                } else {
                    us4 o;
                    o.x = f2bf(acc[mf][nf][0] + b); o.y = f2bf(acc[mf][nf][1] + b);
                    o.z = f2bf(acc[mf][nf][2] + b); o.w = f2bf(acc[mf][nf][3] + b);
                    *(us4*)(VTb + (size_t)n_g * M + m_base) = o;
                }
            }
        }
    } else {
        for (int mf = 0; mf < 4; mf++)
            for (int nf = 0; nf < 4; nf++) {
                int n_g = n0 + wn * 64 + nf * 16 + lr;
                int m_base = m0 + wm * 64 + mf * 16 + rbase;
                for (int r = 0; r < 4; r++)
                    Cf[(size_t)(m_base + r) * N + n_g] = acc[mf][nf][r];
            }
    }
}

// ---------------- causal flash attention (v7b: base-2 softmax) ---------------
// grid (NH, 16); 512 thr = 8 waves; QBLK=128; block (h, by) processes strips
// {31-by, by} sequentially -> exactly 33 identical KV-tile iterations per
// block, 256 blocks, 1/CU. 128 KB LDS (dbuf K[128x128] + VT[128x128]).
// Swapped math (S^T = mfma(K,Q)), in-lane softmax, in-register P (cvt_pk +
// shfl), T13 defer-max, LDS-scratch epilogue. v7b: Q pre-scaled by
// scale*log2e in the QKV GEMM -> NO per-element scale mul, native-base-2
// v_exp (exp2) without the hidden 1/ln2 mul, mask branch is select-only.
__global__ __launch_bounds__(512) void attn(
    const unsigned short* __restrict__ Q, const unsigned short* __restrict__ Kc,
    const unsigned short* __restrict__ VT, unsigned short* __restrict__ O) {
    __shared__ __align__(16) unsigned short SMEM[65536];   // 128 KB
    unsigned short* KB = SMEM;              // [2][128*128]
    unsigned short* VB = SMEM + 32768;      // [2][128*128]
    int h = blockIdx.x;
    int by = blockIdx.y;
    int t = threadIdx.x, lane = t & 63, w = t >> 6;
    int lr = lane & 15, hi = lane >> 4;

    auto stage = [&](int buf, int kv0) {
#pragma unroll
        for (int i = 0; i < 4; i++) {
            int idx = i * 512 + t;            // 0..2047
            int r = idx >> 4, s = idx & 15;   // K: 128 rows x 16 slots
            gl2lds16(Kc + (size_t)(kv0 + r) * HID + h * HD + ((s ^ (r & 7)) << 3),
                     (void*)(KB + buf * 16384 + ((i * 512 + w * 64) << 3)));
        }
#pragma unroll
        for (int i = 0; i < 4; i++) {
            int idx = i * 512 + t;
            int r = idx >> 4, s = idx & 15;   // VT: 128 rows x 16 slots
            gl2lds16(VT + (size_t)(h * HD + r) * SQ + kv0 + ((s ^ (r & 7)) << 3),
                     (void*)(VB + buf * 16384 + ((i * 512 + w * 64) << 3)));
        }
    };

    int strips[2] = {31 - by, by};
    for (int sp = 0; sp < 2; sp++) {
        int strip = strips[sp];
        int qbase = strip * 128;
        int wq0 = qbase + w * 16;
        int qg = wq0 + lr;                 // this lane's q row

        stage(0, 0);
        bf16x8 qf[4];
        for (int ks = 0; ks < 4; ks++)
            qf[ks] = *(const bf16x8*)(Q + (size_t)qg * HID + h * HD + ks * 32 + (hi << 3));
        f32x4 o_acc[8] = {};               // O^T frags: d=16c2+4hi+reg, q=lane&15
        float m_r = -1e30f, l_r = 0.f;
        __syncthreads();

        int nt = strip + 1;                // 128-wide KV tiles for this strip
        int cur = 0;
        for (int tile = 0; tile < nt; tile++) {
            int kv0 = tile * 128;
            if (tile + 1 < nt) stage(cur ^ 1, kv0 + 128);   // async prefetch
            const unsigned short* Kl = KB + cur * 16384;
            const unsigned short* Vl = VB + cur * 16384;

            if (kv0 <= wq0 + 15) {   // not fully above this wave's diagonal
                // S^T = mfma(K, Q): sfr[c][r] = S^T[k=16c+4hi+r][q=lane&15]
                // (already in log2 units: Q pre-scaled by scale*log2e)
                f32x4 sfr[8];
#pragma unroll
                for (int c = 0; c < 8; c++) {
                    f32x4 s = {0.f, 0.f, 0.f, 0.f};
                    __builtin_amdgcn_s_setprio(1);
#pragma unroll
                    for (int ks = 0; ks < 4; ks++) {
                        bf16x8 kf = *(const bf16x8*)(Kl + (c * 16 + lr) * 128 +
                                                     (((ks * 4 + hi) ^ (lr & 7)) << 3));
                        s = __builtin_amdgcn_mfma_f32_16x16x32_bf16(kf, qf[ks], s, 0, 0, 0);
                    }
                    __builtin_amdgcn_s_setprio(0);
                    sfr[c] = s;
                }
                // causal mask (select only; no scale mul needed)
                if (kv0 + 127 > wq0) {
#pragma unroll
                    for (int c = 0; c < 8; c++) {
                        int kgb = kv0 + c * 16 + 4 * hi;
                        for (int r = 0; r < 4; r++)
                            sfr[c][r] = (kgb + r <= qg) ? sfr[c][r] : -1e30f;
                    }
                }
                // in-lane row max (32 values) + cross-hi (2 shfl_xor)
                float mx = -1e30f;
#pragma unroll
                for (int c = 0; c < 8; c++)
                    mx = fmaxf(mx, fmaxf(fmaxf(sfr[c][0], sfr[c][1]),
                                         fmaxf(sfr[c][2], sfr[c][3])));
                mx = fmaxf(mx, __shfl_xor(mx, 16));
                mx = fmaxf(mx, __shfl_xor(mx, 32));
                // T13 defer-max (THR = 8*log2e in log2 units)
                if (__all((mx - m_r) <= 11.5415603f)) {
                    float rs = 0.f;
#pragma unroll
                    for (int c = 0; c < 8; c++)
                        for (int r = 0; r < 4; r++) {
                            float p = __builtin_amdgcn_exp2f(sfr[c][r] - m_r);
                            sfr[c][r] = p;
                            rs += p;
                        }
                    rs += __shfl_xor(rs, 16);
                    rs += __shfl_xor(rs, 32);
                    l_r += rs;
                } else {
                    float mn = fmaxf(m_r, mx);
                    float alpha = __builtin_amdgcn_exp2f(m_r - mn);
                    m_r = mn;
                    float rs = 0.f;
#pragma unroll
                    for (int c = 0; c < 8; c++)
                        for (int r = 0; r < 4; r++) {
                            float p = __builtin_amdgcn_exp2f(sfr[c][r] - mn);
                            sfr[c][r] = p;
                            rs += p;
                        }
                    rs += __shfl_xor(rs, 16);
                    rs += __shfl_xor(rs, 32);
                    l_r = l_r * alpha + rs;
                    for (int c2 = 0; c2 < 8; c2++)
                        for (int r = 0; r < 4; r++) o_acc[c2][r] *= alpha;
                }

                // P^T -> PV B-operand fragments, fully in-register.
                unsigned int wpk[8][2];
#pragma unroll
                for (int c = 0; c < 8; c++)
#pragma unroll
                    for (int i = 0; i < 2; i++) {
                        unsigned int d;
                        asm("v_cvt_pk_bf16_f32 %0, %1, %2"
                            : "=v"(d) : "v"(sfr[c][2 * i]), "v"(sfr[c][2 * i + 1]));
                        wpk[c][i] = d;
                    }
                int srcA = lr + ((hi & 1) << 5);
                int srcB = srcA + 16;
                bool sel = (hi & 2);
#pragma unroll
                for (int kk = 0; kk < 4; kk++) {
                    unsigned int a0 = __shfl(wpk[2 * kk][0], srcA);
                    unsigned int a1 = __shfl(wpk[2 * kk][1], srcA);
                    unsigned int a2 = __shfl(wpk[2 * kk][0], srcB);
                    unsigned int a3 = __shfl(wpk[2 * kk][1], srcB);
                    unsigned int b0 = __shfl(wpk[2 * kk + 1][0], srcA);
                    unsigned int b1 = __shfl(wpk[2 * kk + 1][1], srcA);
                    unsigned int b2 = __shfl(wpk[2 * kk + 1][0], srcB);
                    unsigned int b3 = __shfl(wpk[2 * kk + 1][1], srcB);
                    union { unsigned int u[4]; bf16x8 v; } pf;
                    pf.u[0] = sel ? b0 : a0;
                    pf.u[1] = sel ? b1 : a1;
                    pf.u[2] = sel ? b2 : a2;
                    pf.u[3] = sel ? b3 : a3;
                    // O^T += V^T @ P^T : A = V^T (rows d), B = P^T frag
                    __builtin_amdgcn_s_setprio(1);
#pragma unroll
                    for (int c2 = 0; c2 < 8; c2++) {
                        bf16x8 vv = *(const bf16x8*)(Vl + (c2 * 16 + lr) * 128 +
                                                     (((kk * 4 + hi) ^ (lr & 7)) << 3));
                        o_acc[c2] = __builtin_amdgcn_mfma_f32_16x16x32_bf16(
                            vv, pf.v, o_acc[c2], 0, 0, 0);
                    }
                    __builtin_amdgcn_s_setprio(0);
                }
            }
            __syncthreads();   // drains prefetch vmcnt + syncs buffer flip
            cur ^= 1;
        }

        // epilogue: O^T -> O via per-wave bf16 LDS scratch (within-wave only).
        unsigned short* scr = SMEM + w * 2176;   // 16 rows x 136 bf16
        float invl = 1.0f / l_r;
        for (int c2 = 0; c2 < 8; c2++) {
            us4 o;
            o.x = f2bf(o_acc[c2][0] * invl); o.y = f2bf(o_acc[c2][1] * invl);
            o.z = f2bf(o_acc[c2][2] * invl); o.w = f2bf(o_acc[c2][3] * invl);
            *(us4*)(scr + lr * 136 + c2 * 16 + hi * 4) = o;
        }
        for (int j = 0; j < 4; j++) {
            bf16x8 v = *(const bf16x8*)(scr + lr * 136 + hi * 32 + j * 8);
            *(bf16x8*)(O + (size_t)qg * HID + h * HD + hi * 32 + j * 8) = v;
        }
        __syncthreads();   // scratch reads done before next strip re-stages
    }
}

// ---------------------------------------------------------------------------
extern "C" void kernel_launch(void* const* d_in, const int* in_sizes, int n_in,
                              void* d_out, int out_size, void* d_ws, size_t ws_size,
                              hipStream_t stream) {
    const float* x  = (const float*)d_in[0];
    const float* Wq = (const float*)d_in[1];
    const float* bq = (const float*)d_in[2];
    const float* Wk = (const float*)d_in[3];
    const float* bk = (const float*)d_in[4];
    const float* Wv = (const float*)d_in[5];
    const float* bv = (const float*)d_in[6];
    const float* Wo = (const float*)d_in[7];

    char* ws = (char*)d_ws;
    const size_t MB = 1024 * 1024;
    unsigned short* xb    = (unsigned short*)(ws + 0 * MB);
    unsigned short* WTall = (unsigned short*)(ws + 16 * MB);   // 4 x 8 MB
    unsigned short* Qb    = (unsigned short*)(ws + 48 * MB);
    unsigned short* Kbuf  = (unsigned short*)(ws + 64 * MB);
    unsigned short* VTb   = (unsigned short*)(ws + 80 * MB);
    unsigned short* Ctx   = (unsigned short*)(ws + 96 * MB);

    // 1. merged preprocessing: x -> bf16 (z=4) + 4 weights -> WT bf16 (z<4)
    prep<<<dim3(32, 32, 5), 256, 0, stream>>>(x, Wq, Wk, Wv, Wo, xb, WTall);
    // 2. fused QKV projections (1536 blocks, 2 blocks/CU resident)
    gemm_pipe<0><<<dim3(32, 48), 256, 0, stream>>>(xb, WTall, bq, bk, bv,
                                                   Qb, Kbuf, VTb, nullptr);
    // 3. causal attention (256 identical blocks, 1/CU, v7b base-2 softmax)
    attn<<<dim3(NH, 16), 512, 0, stream>>>(Qb, Kbuf, VTb, Ctx);
    // 4. output projection (512 blocks, 2 blocks/CU resident)
    gemm_pipe<1><<<dim3(32, 16), 256, 0, stream>>>(Ctx, WTall, nullptr, nullptr,
                                                   nullptr, nullptr, nullptr,
                                                   nullptr, (float*)d_out);
}